// Round 9
// baseline (495.265 us; speedup 1.0000x reference)
//
#include <hip/hip_runtime.h>
#include <cstdint>
#include <cstddef>

// ---------------------------------------------------------------------------
// GCN 3-layer forward. bf16 storage + bf16 MFMA gemms, f32 accumulation.
// gemm epilogue pre-scales rows by dinv[row] so aggregation is a pure sum:
//   out[d] = dinv[d] * (sum_{s in N(d)} hs[s] + hs[d]) + bias
// CSR via 128-node buckets (per-block reservation). BN column stats are
// fused into the aggregation kernel (grid-strided, deterministic LDS reduce).
// ---------------------------------------------------------------------------

typedef unsigned int uint32;
typedef __attribute__((ext_vector_type(8))) short bf16x8;
typedef __attribute__((ext_vector_type(4))) float f32x4;

__device__ inline float bl(uint32 u) { uint32 v = u << 16; return __builtin_bit_cast(float, v); }
__device__ inline float bh(uint32 u) { uint32 v = u & 0xffff0000u; return __builtin_bit_cast(float, v); }
__device__ inline uint32 f2b(float f) {   // RNE f32 -> bf16 bits
    uint32 u = __builtin_bit_cast(uint32, f);
    return (u + 0x7fffu + ((u >> 16) & 1u)) >> 16;
}
__device__ inline uint32 pack2(float x, float y) { return f2b(x) | (f2b(y) << 16); }

#define MFMA16(a, b, c) __builtin_amdgcn_mfma_f32_16x16x32_bf16(a, b, c, 0, 0, 0)
#define CSR_CH 4096
#define GSTAT 2048

// ---------------- bucketed CSR build ----------------
// bucket b covers nodes [b*128, b*128+128); packed entry = src | (dst&127)<<17
// bcnt/bcur are padded: counter i lives at [i*16] (one per 64B line).

__global__ __launch_bounds__(256) void bucket_hist(const int* __restrict__ dst,
                                                   int* __restrict__ bcntp,
                                                   int E, int NB) {
    __shared__ int lh[1024];
    for (int t = threadIdx.x; t < NB; t += 256) lh[t] = 0;
    __syncthreads();
    int stride = gridDim.x * 256;
    for (int e = blockIdx.x * 256 + threadIdx.x; e < E; e += stride)
        atomicAdd(&lh[dst[e] >> 7], 1);
    __syncthreads();
    for (int t = threadIdx.x; t < NB; t += 256)
        if (lh[t]) atomicAdd(&bcntp[t * 16], lh[t]);
}

__global__ __launch_bounds__(1024) void bucket_scan(const int* __restrict__ bcntp,
                                                    int* __restrict__ boffs,
                                                    int* __restrict__ bcurp, int nb) {
    __shared__ int s[1024];
    int tx = threadIdx.x;
    int v = (tx < nb) ? bcntp[tx * 16] : 0;
    s[tx] = v;
    __syncthreads();
    for (int off = 1; off < 1024; off <<= 1) {
        int t = (tx >= off) ? s[tx - off] : 0;
        __syncthreads();
        s[tx] += t;
        __syncthreads();
    }
    if (tx < nb) {
        int ex = s[tx] - v;
        boffs[tx] = ex;
        bcurp[tx * 16] = ex;
    }
    if (tx == 0) boffs[nb] = s[1023];
}

// per-block chunk: LDS hist -> one global atomic per touched bucket -> scatter
__global__ __launch_bounds__(256) void bucket_fill2(const int* __restrict__ src,
                                                    const int* __restrict__ dst,
                                                    int* __restrict__ bcurp,
                                                    uint32* __restrict__ bkt,
                                                    int E, int NB) {
    __shared__ int lh[1024];
    __shared__ int lcur[1024];
    int e0 = blockIdx.x * CSR_CH;
    int e1 = e0 + CSR_CH;
    if (e1 > E) e1 = E;
    for (int t = threadIdx.x; t < NB; t += 256) lh[t] = 0;
    __syncthreads();
    for (int e = e0 + threadIdx.x; e < e1; e += 256)
        atomicAdd(&lh[dst[e] >> 7], 1);
    __syncthreads();
    for (int t = threadIdx.x; t < NB; t += 256)
        lcur[t] = lh[t] ? atomicAdd(&bcurp[t * 16], lh[t]) : 0;
    __syncthreads();
    for (int e = e0 + threadIdx.x; e < e1; e += 256) {
        int d = dst[e];
        int b = d >> 7;
        int pos = atomicAdd(&lcur[b], 1);
        bkt[pos] = (uint32)src[e] | ((uint32)(d & 127) << 17);
    }
}

// fused per-bucket finalize: degree count -> dinv -> local scan -> offs -> csr
__global__ __launch_bounds__(256) void bucket_csr(const uint32* __restrict__ bkt,
                                                  const int* __restrict__ boffs,
                                                  float* __restrict__ dinv,
                                                  int* __restrict__ offs,
                                                  int* __restrict__ csr, int n) {
    __shared__ int lcnt[128];
    __shared__ int lscan[128];
    __shared__ int lcur[128];
    int b = blockIdx.x;
    int tx = threadIdx.x;
    if (tx < 128) lcnt[tx] = 0;
    __syncthreads();
    int j0 = boffs[b], j1 = boffs[b + 1];
    for (int j = j0 + tx; j < j1; j += 256)
        atomicAdd(&lcnt[bkt[j] >> 17], 1);
    __syncthreads();
    if (tx < 128) lscan[tx] = lcnt[tx];
    __syncthreads();
    for (int off = 1; off < 128; off <<= 1) {
        int v = 0;
        if (tx < 128 && tx >= off) v = lscan[tx - off];
        __syncthreads();
        if (tx < 128) lscan[tx] += v;
        __syncthreads();
    }
    if (tx < 128) {
        int node = b * 128 + tx;
        if (node < n) {
            int o = j0 + lscan[tx] - lcnt[tx];   // bucket-local exclusive scan
            offs[node] = o;
            lcur[tx] = o;
            dinv[node] = rsqrtf((float)(lcnt[tx] + 1));  // +1 self loop
        }
    }
    if (b == gridDim.x - 1 && tx == 0) offs[n] = j1;   // j1 == E for last bucket
    __syncthreads();
    for (int j = j0 + tx; j < j1; j += 256) {
        uint32 e = bkt[j];
        int dloc = e >> 17;
        int pos = atomicAdd(&lcur[dloc], 1);
        csr[pos] = (int)(e & 0x1FFFFu);
    }
}

// W (f32 [K][Ncol]) -> WT (bf16 [Nout][128]), Ncol<=Nout (pad cols with 0)
__global__ __launch_bounds__(256) void wconv(const float* __restrict__ W1,
                                             const float* __restrict__ W2,
                                             const float* __restrict__ W3,
                                             unsigned short* __restrict__ wt1,
                                             unsigned short* __restrict__ wt2,
                                             unsigned short* __restrict__ wt3) {
    int b = blockIdx.x, tx = threadIdx.x;
    if (b < 2) {
        const float* S = b ? W2 : W1;
        unsigned short* D = b ? wt2 : wt1;
        for (int i = tx; i < 128 * 128; i += 256) {
            int k = i >> 7, nn = i & 127;
            D[nn * 128 + k] = (unsigned short)f2b(S[i]);
        }
    } else {
        for (int i = tx; i < 48 * 128; i += 256) {
            int k = i / 48, nn = i - k * 48;
            float v = (nn < 40) ? W3[k * 40 + nn] : 0.f;
            wt3[nn * 128 + k] = (unsigned short)f2b(v);
        }
    }
}

// ---------------- MFMA gemms ----------------
// LDS chunk addressing: element off = r*128 + ((kb ^ (r&7))<<3), kb = 16B block

// C[r][c] (bf16 packed pairs, n x 128) = bnrelu(A[r][:]) @ W * dinv[r]
template <bool ABF16, bool BN>
__global__ __launch_bounds__(256) void gemm128m(const void* __restrict__ Av,
                                                const unsigned short* __restrict__ WT,
                                                uint32* __restrict__ C,
                                                const float* __restrict__ dinv, int n,
                                                const float* __restrict__ scale,
                                                const float* __restrict__ shift) {
    __shared__ unsigned short Wls[128 * 128];
    __shared__ unsigned short Als[128 * 128];
    int tx = threadIdx.x;
    int row0 = blockIdx.x * 128;
    {   // stage W: 2048 uint4 chunks
        const uint4* srcW = (const uint4*)WT;
#pragma unroll
        for (int i = 0; i < 8; i++) {
            int cid = tx + 256 * i;
            int nr = cid >> 4, kb = cid & 15;
            uint4 u = srcW[cid];
            *(uint4*)&Wls[nr * 128 + ((kb ^ (nr & 7)) << 3)] = u;
        }
    }
    int kb = tx & 15;
    if (ABF16) {
        const uint4* src = (const uint4*)Av;
        float4 sA, sB, hA_, hB_;
        if (BN) {
            sA = ((const float4*)scale)[kb * 2];
            sB = ((const float4*)scale)[kb * 2 + 1];
            hA_ = ((const float4*)shift)[kb * 2];
            hB_ = ((const float4*)shift)[kb * 2 + 1];
        }
#pragma unroll
        for (int i = 0; i < 8; i++) {
            int r = (tx >> 4) + 16 * i;
            int gr = row0 + r;
            if (gr >= n) gr = n - 1;
            uint4 u = src[(size_t)gr * 16 + kb];
            if (BN) {
                uint4 o;
                o.x = pack2(fmaxf(0.f, bl(u.x) * sA.x + hA_.x), fmaxf(0.f, bh(u.x) * sA.y + hA_.y));
                o.y = pack2(fmaxf(0.f, bl(u.y) * sA.z + hA_.z), fmaxf(0.f, bh(u.y) * sA.w + hA_.w));
                o.z = pack2(fmaxf(0.f, bl(u.z) * sB.x + hB_.x), fmaxf(0.f, bh(u.z) * sB.y + hB_.y));
                o.w = pack2(fmaxf(0.f, bl(u.w) * sB.z + hB_.z), fmaxf(0.f, bh(u.w) * sB.w + hB_.w));
                u = o;
            }
            *(uint4*)&Als[r * 128 + ((kb ^ (r & 7)) << 3)] = u;
        }
    } else {
        const float4* src = (const float4*)Av;
#pragma unroll
        for (int i = 0; i < 8; i++) {
            int r = (tx >> 4) + 16 * i;
            int gr = row0 + r;
            if (gr >= n) gr = n - 1;
            float4 a = src[(size_t)gr * 32 + kb * 2];
            float4 b = src[(size_t)gr * 32 + kb * 2 + 1];
            uint4 u;
            u.x = pack2(a.x, a.y);
            u.y = pack2(a.z, a.w);
            u.z = pack2(b.x, b.y);
            u.w = pack2(b.z, b.w);
            *(uint4*)&Als[r * 128 + ((kb ^ (r & 7)) << 3)] = u;
        }
    }
    __syncthreads();

    int w = tx >> 6, lane = tx & 63;
    int r0 = w * 32;
    int lrow = lane & 15, lkg = lane >> 4;
    f32x4 acc[2][8];
#pragma unroll
    for (int rt = 0; rt < 2; rt++)
#pragma unroll
        for (int nt = 0; nt < 8; nt++) acc[rt][nt] = (f32x4){0.f, 0.f, 0.f, 0.f};
#pragma unroll
    for (int ks = 0; ks < 4; ks++) {
        int kbl = ks * 4 + lkg;
        int r = r0 + lrow;
        bf16x8 a0 = *(const bf16x8*)&Als[r * 128 + ((kbl ^ (r & 7)) << 3)];
        int r2 = r0 + 16 + lrow;
        bf16x8 a1 = *(const bf16x8*)&Als[r2 * 128 + ((kbl ^ (r2 & 7)) << 3)];
#pragma unroll
        for (int nt = 0; nt < 8; nt++) {
            int nr = nt * 16 + lrow;
            bf16x8 b = *(const bf16x8*)&Wls[nr * 128 + ((kbl ^ (nr & 7)) << 3)];
            acc[0][nt] = MFMA16(a0, b, acc[0][nt]);
            acc[1][nt] = MFMA16(a1, b, acc[1][nt]);
        }
    }
    // epilogue: per-wave LDS bounce (wave's own A slice, 8KB), then packed store
    float* SL = (float*)&Als[w * 4096];
#pragma unroll
    for (int rt = 0; rt < 2; rt++) {
#pragma unroll
        for (int nt = 0; nt < 8; nt++)
#pragma unroll
            for (int j = 0; j < 4; j++)
                SL[(lkg * 4 + j) * 128 + nt * 16 + lrow] = acc[rt][nt][j];
#pragma unroll
        for (int i = 0; i < 8; i++) {
            int rloc = i * 2 + (lane >> 5);
            int gr = row0 + r0 + rt * 16 + rloc;
            int cq = lane & 31;
            if (gr < n) {
                float dv = dinv[gr];
                float4 v = *(float4*)&SL[rloc * 128 + cq * 4];
                uint2 o;
                o.x = pack2(v.x * dv, v.y * dv);
                o.y = pack2(v.z * dv, v.w * dv);
                *(uint2*)&C[(size_t)gr * 64 + cq * 2] = o;
            }
        }
        if (rt == 0) __builtin_amdgcn_s_waitcnt(0);  // drain before SL reuse
    }
}

// C[n x 40] bf16 = bnrelu(A bf16) @ W3 * dinv[r]  (N padded to 48 in WT3)
__global__ __launch_bounds__(256) void gemm40m(const uint32* __restrict__ A,
                                               const unsigned short* __restrict__ WT,
                                               unsigned short* __restrict__ C,
                                               const float* __restrict__ dinv, int n,
                                               const float* __restrict__ scale,
                                               const float* __restrict__ shift) {
    __shared__ unsigned short Wls[48 * 128];
    __shared__ unsigned short Als[128 * 128];
    int tx = threadIdx.x;
    int row0 = blockIdx.x * 128;
    {
        const uint4* srcW = (const uint4*)WT;
#pragma unroll
        for (int i = 0; i < 3; i++) {
            int cid = tx + 256 * i;
            int nr = cid >> 4, kb = cid & 15;
            uint4 u = srcW[cid];
            *(uint4*)&Wls[nr * 128 + ((kb ^ (nr & 7)) << 3)] = u;
        }
    }
    int kb = tx & 15;
    {
        const uint4* src = (const uint4*)A;
        float4 sA = ((const float4*)scale)[kb * 2];
        float4 sB = ((const float4*)scale)[kb * 2 + 1];
        float4 hA_ = ((const float4*)shift)[kb * 2];
        float4 hB_ = ((const float4*)shift)[kb * 2 + 1];
#pragma unroll
        for (int i = 0; i < 8; i++) {
            int r = (tx >> 4) + 16 * i;
            int gr = row0 + r;
            if (gr >= n) gr = n - 1;
            uint4 u = src[(size_t)gr * 16 + kb];
            uint4 o;
            o.x = pack2(fmaxf(0.f, bl(u.x) * sA.x + hA_.x), fmaxf(0.f, bh(u.x) * sA.y + hA_.y));
            o.y = pack2(fmaxf(0.f, bl(u.y) * sA.z + hA_.z), fmaxf(0.f, bh(u.y) * sA.w + hA_.w));
            o.z = pack2(fmaxf(0.f, bl(u.z) * sB.x + hB_.x), fmaxf(0.f, bh(u.z) * sB.y + hB_.y));
            o.w = pack2(fmaxf(0.f, bl(u.w) * sB.z + hB_.z), fmaxf(0.f, bh(u.w) * sB.w + hB_.w));
            *(uint4*)&Als[r * 128 + ((kb ^ (r & 7)) << 3)] = o;
        }
    }
    __syncthreads();

    int w = tx >> 6, lane = tx & 63;
    int r0 = w * 32;
    int lrow = lane & 15, lkg = lane >> 4;
    f32x4 acc[2][3];
#pragma unroll
    for (int rt = 0; rt < 2; rt++)
#pragma unroll
        for (int nt = 0; nt < 3; nt++) acc[rt][nt] = (f32x4){0.f, 0.f, 0.f, 0.f};
#pragma unroll
    for (int ks = 0; ks < 4; ks++) {
        int kbl = ks * 4 + lkg;
        int r = r0 + lrow;
        bf16x8 a0 = *(const bf16x8*)&Als[r * 128 + ((kbl ^ (r & 7)) << 3)];
        int r2 = r0 + 16 + lrow;
        bf16x8 a1 = *(const bf16x8*)&Als[r2 * 128 + ((kbl ^ (r2 & 7)) << 3)];
#pragma unroll
        for (int nt = 0; nt < 3; nt++) {
            int nr = nt * 16 + lrow;
            bf16x8 b = *(const bf16x8*)&Wls[nr * 128 + ((kbl ^ (nr & 7)) << 3)];
            acc[0][nt] = MFMA16(a0, b, acc[0][nt]);
            acc[1][nt] = MFMA16(a1, b, acc[1][nt]);
        }
    }
#pragma unroll
    for (int rt = 0; rt < 2; rt++)
#pragma unroll
        for (int j = 0; j < 4; j++) {
            int gr = row0 + r0 + rt * 16 + lkg * 4 + j;
            if (gr < n) {
                float dv = dinv[gr];
#pragma unroll
                for (int nt = 0; nt < 3; nt++) {
                    int col = nt * 16 + lrow;
                    if (col < 40)
                        C[(size_t)gr * 40 + col] = (unsigned short)f2b(acc[rt][nt][j] * dv);
                }
            }
        }
}

// ---------------- aggregation (fused BN column stats) ----------------

// out[d] = pack( dinv[d] * (sum hs[s] + hs[d]) + bias ), 128 bf16 cols.
// Grid-strided (GSTAT blocks x 4 waves); per-lane column stats on the f32
// values pre-pack, LDS-reduced per block -> psum/psq[block][128].
__global__ __launch_bounds__(256) void agg128s(const uint32* __restrict__ h,
                                               const int* __restrict__ csr,
                                               const int* __restrict__ offs,
                                               const float* __restrict__ dinv,
                                               const float* __restrict__ bias,
                                               uint32* __restrict__ out,
                                               float* __restrict__ psum,
                                               float* __restrict__ psq, int n) {
    int w = threadIdx.x >> 6;
    int lane = threadIdx.x & 63;
    int half = lane >> 5;       // 0: even edges, 1: odd edges
    int t = lane & 31;          // uint2 index within row (cols 4t..4t+3)
    const uint2* h2 = (const uint2*)h;
    float4 bb = ((const float4*)bias)[t];
    float s0 = 0.f, s1 = 0.f, s2 = 0.f, s3 = 0.f;   // column stats (half 0)
    float q0 = 0.f, q1 = 0.f, q2 = 0.f, q3 = 0.f;
    for (int wid = blockIdx.x * 4 + w; wid < n; wid += gridDim.x * 4) {
        float a0 = 0.f, a1 = 0.f, a2 = 0.f, a3 = 0.f;   // chain A
        float c0 = 0.f, c1 = 0.f, c2 = 0.f, c3 = 0.f;   // chain B
        if (half == 0) {        // self term
            uint2 u = h2[(size_t)wid * 32 + t];
            a0 = bl(u.x); a1 = bh(u.x); a2 = bl(u.y); a3 = bh(u.y);
        }
        int e0 = offs[wid], e1 = offs[wid + 1];
        int e = e0;
        while (e < e1) {        // wave-uniform
            int cnt = e1 - e;
            if (cnt > 64) cnt = 64;
            int sl = (lane < cnt) ? csr[e + lane] : 0;
            int j = 0;
            for (; j + 3 < cnt; j += 4) {       // 4 edges per iter, convergent
                int sa = __shfl(sl, j + half, 64);
                int sb = __shfl(sl, j + 2 + half, 64);
                uint2 ua = h2[(size_t)sa * 32 + t];
                uint2 ub = h2[(size_t)sb * 32 + t];
                a0 += bl(ua.x); a1 += bh(ua.x); a2 += bl(ua.y); a3 += bh(ua.y);
                c0 += bl(ub.x); c1 += bh(ub.x); c2 += bl(ub.y); c3 += bh(ub.y);
            }
            for (; j < cnt; j++) {              // leftovers, alternate halves
                int s = __shfl(sl, j, 64);      // convergent
                if (half == (j & 1)) {
                    uint2 u = h2[(size_t)s * 32 + t];
                    a0 += bl(u.x); a1 += bh(u.x); a2 += bl(u.y); a3 += bh(u.y);
                }
            }
            e += cnt;
        }
        a0 += c0; a1 += c1; a2 += c2; a3 += c3;
        a0 += __shfl_xor(a0, 32, 64);           // combine halves (convergent)
        a1 += __shfl_xor(a1, 32, 64);
        a2 += __shfl_xor(a2, 32, 64);
        a3 += __shfl_xor(a3, 32, 64);
        if (half == 0) {
            float di = dinv[wid];
            float v0 = a0 * di + bb.x;
            float v1 = a1 * di + bb.y;
            float v2 = a2 * di + bb.z;
            float v3 = a3 * di + bb.w;
            s0 += v0; q0 += v0 * v0;
            s1 += v1; q1 += v1 * v1;
            s2 += v2; q2 += v2 * v2;
            s3 += v3; q3 += v3 * v3;
            uint2 o;
            o.x = pack2(v0, v1);
            o.y = pack2(v2, v3);
            ((uint2*)out)[(size_t)wid * 32 + t] = o;
        }
    }
    // deterministic block reduce: [4 waves][32 cols-quads][4]
    __shared__ float LS[4][32][4], LQ[4][32][4];
    if (half == 0) {
        LS[w][t][0] = s0; LS[w][t][1] = s1; LS[w][t][2] = s2; LS[w][t][3] = s3;
        LQ[w][t][0] = q0; LQ[w][t][1] = q1; LQ[w][t][2] = q2; LQ[w][t][3] = q3;
    }
    __syncthreads();
    if (threadIdx.x < 128) {
        int cq = threadIdx.x >> 2, j = threadIdx.x & 3;
        float S = 0.f, Q = 0.f;
#pragma unroll
        for (int g = 0; g < 4; g++) { S += LS[g][cq][j]; Q += LQ[g][cq][j]; }
        psum[blockIdx.x * 128 + threadIdx.x] = S;
        psq[blockIdx.x * 128 + threadIdx.x] = Q;
    }
}

// 40-col aggregation + bias + log_softmax.  6 groups x 10 lanes, uint2 loads,
// 12 edges/iteration.  FULLY CONVERGENT shfls (clamped source, predicated loads).
__global__ __launch_bounds__(256) void agg40_lsm(const uint32* __restrict__ h,
                                                 const int* __restrict__ csr,
                                                 const int* __restrict__ offs,
                                                 const float* __restrict__ dinv,
                                                 const float* __restrict__ bias,
                                                 float* __restrict__ out, int n) {
    int wid = (blockIdx.x * 256 + threadIdx.x) >> 6;
    int lane = threadIdx.x & 63;
    if (wid >= n) return;
    int grp = lane / 10;              // 0..5 work; 6 (lanes 60-63) idle
    int t = lane - grp * 10;          // uint2 index within row (cols 4t..4t+3)
    bool work = grp < 6;
    const uint2* h2 = (const uint2*)h;
    float a0 = 0.f, a1 = 0.f, a2 = 0.f, a3 = 0.f;
    if (grp == 0) {                   // self term once
        uint2 u = h2[(size_t)wid * 10 + t];
        a0 = bl(u.x); a1 = bh(u.x); a2 = bl(u.y); a3 = bh(u.y);
    }
    int e0 = offs[wid], e1 = offs[wid + 1];
    int e = e0;
    while (e < e1) {                  // wave-uniform
        int cnt = e1 - e;
        if (cnt > 64) cnt = 64;
        int sl = (lane < cnt) ? csr[e + lane] : 0;
        int nIt = (cnt + 11) / 12;    // wave-uniform trip count
        for (int it = 0; it < nIt; it++) {
            int j0 = it * 12 + grp;
            int j1 = j0 + 6;
            int s0 = __shfl(sl, (j0 < cnt) ? j0 : 0, 64);   // convergent
            int s1 = __shfl(sl, (j1 < cnt) ? j1 : 0, 64);   // convergent
            if (work && j0 < cnt) {
                uint2 u = h2[(size_t)s0 * 10 + t];
                a0 += bl(u.x); a1 += bh(u.x); a2 += bl(u.y); a3 += bh(u.y);
            }
            if (work && j1 < cnt) {
                uint2 u = h2[(size_t)s1 * 10 + t];
                a0 += bl(u.x); a1 += bh(u.x); a2 += bl(u.y); a3 += bh(u.y);
            }
        }
        e += cnt;
    }
    // combine 6 groups: g += g+3, then grp0 += grp1 + grp2 (all convergent)
    a0 += __shfl(a0, (lane + 30) & 63, 64);
    a1 += __shfl(a1, (lane + 30) & 63, 64);
    a2 += __shfl(a2, (lane + 30) & 63, 64);
    a3 += __shfl(a3, (lane + 30) & 63, 64);
    {
        float t0 = __shfl(a0, (lane + 10) & 63, 64), u0 = __shfl(a0, (lane + 20) & 63, 64);
        float t1 = __shfl(a1, (lane + 10) & 63, 64), u1 = __shfl(a1, (lane + 20) & 63, 64);
        float t2 = __shfl(a2, (lane + 10) & 63, 64), u2 = __shfl(a2, (lane + 20) & 63, 64);
        float t3 = __shfl(a3, (lane + 10) & 63, 64), u3 = __shfl(a3, (lane + 20) & 63, 64);
        a0 += t0 + u0; a1 += t1 + u1; a2 += t2 + u2; a3 += t3 + u3;
    }
    bool act = lane < 10;
    float di = dinv[wid];
    float v0 = -1e30f, v1 = -1e30f, v2 = -1e30f, v3 = -1e30f;
    if (act) {
        float4 bb = ((const float4*)bias)[t];
        v0 = a0 * di + bb.x;
        v1 = a1 * di + bb.y;
        v2 = a2 * di + bb.z;
        v3 = a3 * di + bb.w;
    }
    float m = fmaxf(fmaxf(v0, v1), fmaxf(v2, v3));
    for (int off = 8; off; off >>= 1) m = fmaxf(m, __shfl_xor(m, off, 64));
    float ss = act ? (expf(v0 - m) + expf(v1 - m) + expf(v2 - m) + expf(v3 - m)) : 0.f;
    for (int off = 8; off; off >>= 1) ss += __shfl_xor(ss, off, 64);
    float lg = logf(ss);
    if (act) {
        float4 o = {v0 - m - lg, v1 - m - lg, v2 - m - lg, v3 - m - lg};
        *(float4*)&out[(size_t)wid * 40 + t * 4] = o;
    }
}

// ---------------- BN stats finalize ----------------

__global__ __launch_bounds__(1024) void finalize_stats(const float* __restrict__ psum,
                                                       const float* __restrict__ psq,
                                                       const float* __restrict__ g,
                                                       const float* __restrict__ be,
                                                       float* __restrict__ scale,
                                                       float* __restrict__ shift,
                                                       int nb, float invN) {
    int c = threadIdx.x & 127;
    int seg = threadIdx.x >> 7;       // 0..7
    int per = nb >> 3;
    float s = 0.f, q = 0.f;
    for (int b = seg * per; b < (seg + 1) * per; b++) {
        s += psum[b * 128 + c];
        q += psq[b * 128 + c];
    }
    __shared__ float LS[8][128], LQ[8][128];
    LS[seg][c] = s;
    LQ[seg][c] = q;
    __syncthreads();
    if (threadIdx.x < 128) {
        float S = 0.f, Q = 0.f;
#pragma unroll
        for (int g2 = 0; g2 < 8; g2++) { S += LS[g2][c]; Q += LQ[g2][c]; }
        float mu = S * invN;
        float var = Q * invN - mu * mu;
        float sc = g[c] * rsqrtf(var + 1e-5f);
        scale[c] = sc;
        shift[c] = be[c] - mu * sc;
    }
}

extern "C" void kernel_launch(void* const* d_in, const int* in_sizes, int n_in,
                              void* d_out, int out_size, void* d_ws, size_t ws_size,
                              hipStream_t stream) {
    const float* x   = (const float*)d_in[0];
    const float* W1  = (const float*)d_in[1];
    const float* b1  = (const float*)d_in[2];
    const float* W2  = (const float*)d_in[3];
    const float* b2  = (const float*)d_in[4];
    const float* W3  = (const float*)d_in[5];
    const float* b3  = (const float*)d_in[6];
    const float* g1  = (const float*)d_in[7];
    const float* be1 = (const float*)d_in[8];
    const float* g2  = (const float*)d_in[9];
    const float* be2 = (const float*)d_in[10];
    const int*   ei  = (const int*)d_in[11];

    int n = in_sizes[0] / 128;
    int E = in_sizes[11] / 2;
    const int* src = ei;
    const int* dst = ei + E;
    int NB = (n + 127) >> 7;            // 128-node buckets

    char* p = (char*)d_ws;
    size_t off = 0;
    auto alloc = [&](size_t bytes) -> void* {
        off = (off + 255) & ~(size_t)255;
        void* r = p + off;
        off += bytes;
        return r;
    };
    uint32* hA    = (uint32*)alloc((size_t)n * 64 * 4);   // n x 128 bf16
    uint32* hB    = (uint32*)alloc((size_t)n * 64 * 4);
    float* dinv   = (float*)alloc((size_t)n * 4);
    int*   offs   = (int*)alloc((size_t)(n + 1) * 4);
    int*   csr    = (int*)alloc((size_t)E * 4);
    float* psum   = (float*)alloc((size_t)GSTAT * 128 * 4);
    float* psq    = (float*)alloc((size_t)GSTAT * 128 * 4);
    float* scale  = (float*)alloc(128 * 4);
    float* shift  = (float*)alloc(128 * 4);
    unsigned short* wt1 = (unsigned short*)alloc(128 * 128 * 2);
    unsigned short* wt2 = (unsigned short*)alloc(128 * 128 * 2);
    unsigned short* wt3 = (unsigned short*)alloc(48 * 128 * 2);
    int*   bcntp  = (int*)alloc((size_t)NB * 16 * 4);     // padded: 1 counter / 64B
    int*   boffs  = (int*)alloc((size_t)(NB + 1) * 4);
    int*   bcurp  = (int*)alloc((size_t)NB * 16 * 4);     // padded
    // bkt aliases hA: dead before the first gemm writes hA (stream-ordered)
    uint32* bkt   = hA;
    (void)ws_size;

    int gG = (n + 127) / 128;           // mfma-gemm blocks
    int gAgg = (n * 64 + 255) / 256;
    int gFill = (E + CSR_CH - 1) / CSR_CH;
    float invN = 1.0f / (float)n;

    hipMemsetAsync(bcntp, 0, (size_t)NB * 16 * 4, stream);

    wconv<<<3, 256, 0, stream>>>(W1, W2, W3, wt1, wt2, wt3);
    bucket_hist<<<256, 256, 0, stream>>>(dst, bcntp, E, NB);
    bucket_scan<<<1, 1024, 0, stream>>>(bcntp, boffs, bcurp, NB);
    bucket_fill2<<<gFill, 256, 0, stream>>>(src, dst, bcurp, bkt, E, NB);
    bucket_csr<<<NB, 256, 0, stream>>>(bkt, boffs, dinv, offs, csr, n);

    // layer 1
    gemm128m<false, false><<<gG, 256, 0, stream>>>(x, wt1, hA, dinv, n, nullptr, nullptr);
    agg128s<<<GSTAT, 256, 0, stream>>>(hA, csr, offs, dinv, b1, hB, psum, psq, n);
    finalize_stats<<<1, 1024, 0, stream>>>(psum, psq, g1, be1, scale, shift, GSTAT, invN);

    // layer 2
    gemm128m<true, true><<<gG, 256, 0, stream>>>(hB, wt2, hA, dinv, n, scale, shift);
    agg128s<<<GSTAT, 256, 0, stream>>>(hA, csr, offs, dinv, b2, hB, psum, psq, n);
    finalize_stats<<<1, 1024, 0, stream>>>(psum, psq, g2, be2, scale, shift, GSTAT, invN);

    // layer 3 + log_softmax
    gemm40m<<<gG, 256, 0, stream>>>(hB, wt3, (unsigned short*)hA, dinv, n, scale, shift);
    agg40_lsm<<<gAgg, 256, 0, stream>>>(hA, csr, offs, dinv, b3, (float*)d_out, n);
}

// Round 10
// 356.510 us; speedup vs baseline: 1.3892x; 1.3892x over previous
//
#include <hip/hip_runtime.h>
#include <cstdint>
#include <cstddef>

// ---------------------------------------------------------------------------
// GCN 3-layer forward. bf16 storage + bf16 MFMA gemms, f32 accumulation.
// gemm epilogue pre-scales rows by dinv[row] so aggregation is a pure sum:
//   out[d] = dinv[d] * (sum_{s in N(d)} hs[s] + hs[d]) + bias
// CSR via 128-node buckets (per-block reservation). BN column stats fused
// into aggregation; partials reduced in two parallel stages.
// ---------------------------------------------------------------------------

typedef unsigned int uint32;
typedef __attribute__((ext_vector_type(8))) short bf16x8;
typedef __attribute__((ext_vector_type(4))) float f32x4;

__device__ inline float bl(uint32 u) { uint32 v = u << 16; return __builtin_bit_cast(float, v); }
__device__ inline float bh(uint32 u) { uint32 v = u & 0xffff0000u; return __builtin_bit_cast(float, v); }
__device__ inline uint32 f2b(float f) {   // RNE f32 -> bf16 bits
    uint32 u = __builtin_bit_cast(uint32, f);
    return (u + 0x7fffu + ((u >> 16) & 1u)) >> 16;
}
__device__ inline uint32 pack2(float x, float y) { return f2b(x) | (f2b(y) << 16); }

#define MFMA16(a, b, c) __builtin_amdgcn_mfma_f32_16x16x32_bf16(a, b, c, 0, 0, 0)
#define CSR_CH 4096
#define GSTAT 2048

// ---------------- bucketed CSR build ----------------
// bucket b covers nodes [b*128, b*128+128); packed entry = src | (dst&127)<<17
// bcnt/bcur are padded: counter i lives at [i*16] (one per 64B line).

__global__ __launch_bounds__(256) void bucket_hist(const int* __restrict__ dst,
                                                   int* __restrict__ bcntp,
                                                   int E, int NB) {
    __shared__ int lh[1024];
    for (int t = threadIdx.x; t < NB; t += 256) lh[t] = 0;
    __syncthreads();
    int stride = gridDim.x * 256;
    for (int e = blockIdx.x * 256 + threadIdx.x; e < E; e += stride)
        atomicAdd(&lh[dst[e] >> 7], 1);
    __syncthreads();
    for (int t = threadIdx.x; t < NB; t += 256)
        if (lh[t]) atomicAdd(&bcntp[t * 16], lh[t]);
}

__global__ __launch_bounds__(1024) void bucket_scan(const int* __restrict__ bcntp,
                                                    int* __restrict__ boffs,
                                                    int* __restrict__ bcurp, int nb) {
    __shared__ int s[1024];
    int tx = threadIdx.x;
    int v = (tx < nb) ? bcntp[tx * 16] : 0;
    s[tx] = v;
    __syncthreads();
    for (int off = 1; off < 1024; off <<= 1) {
        int t = (tx >= off) ? s[tx - off] : 0;
        __syncthreads();
        s[tx] += t;
        __syncthreads();
    }
    if (tx < nb) {
        int ex = s[tx] - v;
        boffs[tx] = ex;
        bcurp[tx * 16] = ex;
    }
    if (tx == 0) boffs[nb] = s[1023];
}

// per-block chunk: LDS hist -> one global atomic per touched bucket -> scatter
__global__ __launch_bounds__(256) void bucket_fill2(const int* __restrict__ src,
                                                    const int* __restrict__ dst,
                                                    int* __restrict__ bcurp,
                                                    uint32* __restrict__ bkt,
                                                    int E, int NB) {
    __shared__ int lh[1024];
    __shared__ int lcur[1024];
    int e0 = blockIdx.x * CSR_CH;
    int e1 = e0 + CSR_CH;
    if (e1 > E) e1 = E;
    for (int t = threadIdx.x; t < NB; t += 256) lh[t] = 0;
    __syncthreads();
    for (int e = e0 + threadIdx.x; e < e1; e += 256)
        atomicAdd(&lh[dst[e] >> 7], 1);
    __syncthreads();
    for (int t = threadIdx.x; t < NB; t += 256)
        lcur[t] = lh[t] ? atomicAdd(&bcurp[t * 16], lh[t]) : 0;
    __syncthreads();
    for (int e = e0 + threadIdx.x; e < e1; e += 256) {
        int d = dst[e];
        int b = d >> 7;
        int pos = atomicAdd(&lcur[b], 1);
        bkt[pos] = (uint32)src[e] | ((uint32)(d & 127) << 17);
    }
}

// fused per-bucket finalize: degree count -> dinv -> local scan -> offs -> csr
__global__ __launch_bounds__(256) void bucket_csr(const uint32* __restrict__ bkt,
                                                  const int* __restrict__ boffs,
                                                  float* __restrict__ dinv,
                                                  int* __restrict__ offs,
                                                  int* __restrict__ csr, int n) {
    __shared__ int lcnt[128];
    __shared__ int lscan[128];
    __shared__ int lcur[128];
    int b = blockIdx.x;
    int tx = threadIdx.x;
    if (tx < 128) lcnt[tx] = 0;
    __syncthreads();
    int j0 = boffs[b], j1 = boffs[b + 1];
    for (int j = j0 + tx; j < j1; j += 256)
        atomicAdd(&lcnt[bkt[j] >> 17], 1);
    __syncthreads();
    if (tx < 128) lscan[tx] = lcnt[tx];
    __syncthreads();
    for (int off = 1; off < 128; off <<= 1) {
        int v = 0;
        if (tx < 128 && tx >= off) v = lscan[tx - off];
        __syncthreads();
        if (tx < 128) lscan[tx] += v;
        __syncthreads();
    }
    if (tx < 128) {
        int node = b * 128 + tx;
        if (node < n) {
            int o = j0 + lscan[tx] - lcnt[tx];   // bucket-local exclusive scan
            offs[node] = o;
            lcur[tx] = o;
            dinv[node] = rsqrtf((float)(lcnt[tx] + 1));  // +1 self loop
        }
    }
    if (b == gridDim.x - 1 && tx == 0) offs[n] = j1;   // j1 == E for last bucket
    __syncthreads();
    for (int j = j0 + tx; j < j1; j += 256) {
        uint32 e = bkt[j];
        int dloc = e >> 17;
        int pos = atomicAdd(&lcur[dloc], 1);
        csr[pos] = (int)(e & 0x1FFFFu);
    }
}

// W (f32 [K][Ncol]) -> WT (bf16 [Nout][128]), Ncol<=Nout (pad cols with 0)
__global__ __launch_bounds__(256) void wconv(const float* __restrict__ W1,
                                             const float* __restrict__ W2,
                                             const float* __restrict__ W3,
                                             unsigned short* __restrict__ wt1,
                                             unsigned short* __restrict__ wt2,
                                             unsigned short* __restrict__ wt3) {
    int b = blockIdx.x, tx = threadIdx.x;
    if (b < 2) {
        const float* S = b ? W2 : W1;
        unsigned short* D = b ? wt2 : wt1;
        for (int i = tx; i < 128 * 128; i += 256) {
            int k = i >> 7, nn = i & 127;
            D[nn * 128 + k] = (unsigned short)f2b(S[i]);
        }
    } else {
        for (int i = tx; i < 48 * 128; i += 256) {
            int k = i / 48, nn = i - k * 48;
            float v = (nn < 40) ? W3[k * 40 + nn] : 0.f;
            wt3[nn * 128 + k] = (unsigned short)f2b(v);
        }
    }
}

// ---------------- MFMA gemms ----------------
// LDS chunk addressing: element off = r*128 + ((kb ^ (r&7))<<3), kb = 16B block

// C[r][c] (bf16 packed pairs, n x 128) = bnrelu(A[r][:]) @ W * dinv[r]
template <bool ABF16, bool BN>
__global__ __launch_bounds__(256) void gemm128m(const void* __restrict__ Av,
                                                const unsigned short* __restrict__ WT,
                                                uint32* __restrict__ C,
                                                const float* __restrict__ dinv, int n,
                                                const float* __restrict__ scale,
                                                const float* __restrict__ shift) {
    __shared__ unsigned short Wls[128 * 128];
    __shared__ unsigned short Als[128 * 128];
    int tx = threadIdx.x;
    int row0 = blockIdx.x * 128;
    {   // stage W: 2048 uint4 chunks
        const uint4* srcW = (const uint4*)WT;
#pragma unroll
        for (int i = 0; i < 8; i++) {
            int cid = tx + 256 * i;
            int nr = cid >> 4, kb = cid & 15;
            uint4 u = srcW[cid];
            *(uint4*)&Wls[nr * 128 + ((kb ^ (nr & 7)) << 3)] = u;
        }
    }
    int kb = tx & 15;
    if (ABF16) {
        const uint4* src = (const uint4*)Av;
        float4 sA, sB, hA_, hB_;
        if (BN) {
            sA = ((const float4*)scale)[kb * 2];
            sB = ((const float4*)scale)[kb * 2 + 1];
            hA_ = ((const float4*)shift)[kb * 2];
            hB_ = ((const float4*)shift)[kb * 2 + 1];
        }
#pragma unroll
        for (int i = 0; i < 8; i++) {
            int r = (tx >> 4) + 16 * i;
            int gr = row0 + r;
            if (gr >= n) gr = n - 1;
            uint4 u = src[(size_t)gr * 16 + kb];
            if (BN) {
                uint4 o;
                o.x = pack2(fmaxf(0.f, bl(u.x) * sA.x + hA_.x), fmaxf(0.f, bh(u.x) * sA.y + hA_.y));
                o.y = pack2(fmaxf(0.f, bl(u.y) * sA.z + hA_.z), fmaxf(0.f, bh(u.y) * sA.w + hA_.w));
                o.z = pack2(fmaxf(0.f, bl(u.z) * sB.x + hB_.x), fmaxf(0.f, bh(u.z) * sB.y + hB_.y));
                o.w = pack2(fmaxf(0.f, bl(u.w) * sB.z + hB_.z), fmaxf(0.f, bh(u.w) * sB.w + hB_.w));
                u = o;
            }
            *(uint4*)&Als[r * 128 + ((kb ^ (r & 7)) << 3)] = u;
        }
    } else {
        const float4* src = (const float4*)Av;
#pragma unroll
        for (int i = 0; i < 8; i++) {
            int r = (tx >> 4) + 16 * i;
            int gr = row0 + r;
            if (gr >= n) gr = n - 1;
            float4 a = src[(size_t)gr * 32 + kb * 2];
            float4 b = src[(size_t)gr * 32 + kb * 2 + 1];
            uint4 u;
            u.x = pack2(a.x, a.y);
            u.y = pack2(a.z, a.w);
            u.z = pack2(b.x, b.y);
            u.w = pack2(b.z, b.w);
            *(uint4*)&Als[r * 128 + ((kb ^ (r & 7)) << 3)] = u;
        }
    }
    __syncthreads();

    int w = tx >> 6, lane = tx & 63;
    int r0 = w * 32;
    int lrow = lane & 15, lkg = lane >> 4;
    f32x4 acc[2][8];
#pragma unroll
    for (int rt = 0; rt < 2; rt++)
#pragma unroll
        for (int nt = 0; nt < 8; nt++) acc[rt][nt] = (f32x4){0.f, 0.f, 0.f, 0.f};
#pragma unroll
    for (int ks = 0; ks < 4; ks++) {
        int kbl = ks * 4 + lkg;
        int r = r0 + lrow;
        bf16x8 a0 = *(const bf16x8*)&Als[r * 128 + ((kbl ^ (r & 7)) << 3)];
        int r2 = r0 + 16 + lrow;
        bf16x8 a1 = *(const bf16x8*)&Als[r2 * 128 + ((kbl ^ (r2 & 7)) << 3)];
#pragma unroll
        for (int nt = 0; nt < 8; nt++) {
            int nr = nt * 16 + lrow;
            bf16x8 b = *(const bf16x8*)&Wls[nr * 128 + ((kbl ^ (nr & 7)) << 3)];
            acc[0][nt] = MFMA16(a0, b, acc[0][nt]);
            acc[1][nt] = MFMA16(a1, b, acc[1][nt]);
        }
    }
    // epilogue: per-wave LDS bounce (wave's own A slice, 8KB), then packed store
    float* SL = (float*)&Als[w * 4096];
#pragma unroll
    for (int rt = 0; rt < 2; rt++) {
#pragma unroll
        for (int nt = 0; nt < 8; nt++)
#pragma unroll
            for (int j = 0; j < 4; j++)
                SL[(lkg * 4 + j) * 128 + nt * 16 + lrow] = acc[rt][nt][j];
#pragma unroll
        for (int i = 0; i < 8; i++) {
            int rloc = i * 2 + (lane >> 5);
            int gr = row0 + r0 + rt * 16 + rloc;
            int cq = lane & 31;
            if (gr < n) {
                float dv = dinv[gr];
                float4 v = *(float4*)&SL[rloc * 128 + cq * 4];
                uint2 o;
                o.x = pack2(v.x * dv, v.y * dv);
                o.y = pack2(v.z * dv, v.w * dv);
                *(uint2*)&C[(size_t)gr * 64 + cq * 2] = o;
            }
        }
        if (rt == 0) __builtin_amdgcn_s_waitcnt(0);  // drain before SL reuse
    }
}

// C[n x 40] bf16 = bnrelu(A bf16) @ W3 * dinv[r]  (N padded to 48 in WT3)
__global__ __launch_bounds__(256) void gemm40m(const uint32* __restrict__ A,
                                               const unsigned short* __restrict__ WT,
                                               unsigned short* __restrict__ C,
                                               const float* __restrict__ dinv, int n,
                                               const float* __restrict__ scale,
                                               const float* __restrict__ shift) {
    __shared__ unsigned short Wls[48 * 128];
    __shared__ unsigned short Als[128 * 128];
    int tx = threadIdx.x;
    int row0 = blockIdx.x * 128;
    {
        const uint4* srcW = (const uint4*)WT;
#pragma unroll
        for (int i = 0; i < 3; i++) {
            int cid = tx + 256 * i;
            int nr = cid >> 4, kb = cid & 15;
            uint4 u = srcW[cid];
            *(uint4*)&Wls[nr * 128 + ((kb ^ (nr & 7)) << 3)] = u;
        }
    }
    int kb = tx & 15;
    {
        const uint4* src = (const uint4*)A;
        float4 sA = ((const float4*)scale)[kb * 2];
        float4 sB = ((const float4*)scale)[kb * 2 + 1];
        float4 hA_ = ((const float4*)shift)[kb * 2];
        float4 hB_ = ((const float4*)shift)[kb * 2 + 1];
#pragma unroll
        for (int i = 0; i < 8; i++) {
            int r = (tx >> 4) + 16 * i;
            int gr = row0 + r;
            if (gr >= n) gr = n - 1;
            uint4 u = src[(size_t)gr * 16 + kb];
            uint4 o;
            o.x = pack2(fmaxf(0.f, bl(u.x) * sA.x + hA_.x), fmaxf(0.f, bh(u.x) * sA.y + hA_.y));
            o.y = pack2(fmaxf(0.f, bl(u.y) * sA.z + hA_.z), fmaxf(0.f, bh(u.y) * sA.w + hA_.w));
            o.z = pack2(fmaxf(0.f, bl(u.z) * sB.x + hB_.x), fmaxf(0.f, bh(u.z) * sB.y + hB_.y));
            o.w = pack2(fmaxf(0.f, bl(u.w) * sB.z + hB_.z), fmaxf(0.f, bh(u.w) * sB.w + hB_.w));
            *(uint4*)&Als[r * 128 + ((kb ^ (r & 7)) << 3)] = o;
        }
    }
    __syncthreads();

    int w = tx >> 6, lane = tx & 63;
    int r0 = w * 32;
    int lrow = lane & 15, lkg = lane >> 4;
    f32x4 acc[2][3];
#pragma unroll
    for (int rt = 0; rt < 2; rt++)
#pragma unroll
        for (int nt = 0; nt < 3; nt++) acc[rt][nt] = (f32x4){0.f, 0.f, 0.f, 0.f};
#pragma unroll
    for (int ks = 0; ks < 4; ks++) {
        int kbl = ks * 4 + lkg;
        int r = r0 + lrow;
        bf16x8 a0 = *(const bf16x8*)&Als[r * 128 + ((kbl ^ (r & 7)) << 3)];
        int r2 = r0 + 16 + lrow;
        bf16x8 a1 = *(const bf16x8*)&Als[r2 * 128 + ((kbl ^ (r2 & 7)) << 3)];
#pragma unroll
        for (int nt = 0; nt < 3; nt++) {
            int nr = nt * 16 + lrow;
            bf16x8 b = *(const bf16x8*)&Wls[nr * 128 + ((kbl ^ (nr & 7)) << 3)];
            acc[0][nt] = MFMA16(a0, b, acc[0][nt]);
            acc[1][nt] = MFMA16(a1, b, acc[1][nt]);
        }
    }
#pragma unroll
    for (int rt = 0; rt < 2; rt++)
#pragma unroll
        for (int j = 0; j < 4; j++) {
            int gr = row0 + r0 + rt * 16 + lkg * 4 + j;
            if (gr < n) {
                float dv = dinv[gr];
#pragma unroll
                for (int nt = 0; nt < 3; nt++) {
                    int col = nt * 16 + lrow;
                    if (col < 40)
                        C[(size_t)gr * 40 + col] = (unsigned short)f2b(acc[rt][nt][j] * dv);
                }
            }
        }
}

// ---------------- aggregation (fused BN column stats) ----------------

// out[d] = pack( dinv[d] * (sum hs[s] + hs[d]) + bias ), 128 bf16 cols.
// Grid-strided (GSTAT blocks x 4 waves); per-lane column stats on the f32
// values pre-pack, LDS-reduced per block -> psum/psq[block][128].
__global__ __launch_bounds__(256) void agg128s(const uint32* __restrict__ h,
                                               const int* __restrict__ csr,
                                               const int* __restrict__ offs,
                                               const float* __restrict__ dinv,
                                               const float* __restrict__ bias,
                                               uint32* __restrict__ out,
                                               float* __restrict__ psum,
                                               float* __restrict__ psq, int n) {
    int w = threadIdx.x >> 6;
    int lane = threadIdx.x & 63;
    int half = lane >> 5;       // 0: even edges, 1: odd edges
    int t = lane & 31;          // uint2 index within row (cols 4t..4t+3)
    const uint2* h2 = (const uint2*)h;
    float4 bb = ((const float4*)bias)[t];
    float s0 = 0.f, s1 = 0.f, s2 = 0.f, s3 = 0.f;   // column stats (half 0)
    float q0 = 0.f, q1 = 0.f, q2 = 0.f, q3 = 0.f;
    for (int wid = blockIdx.x * 4 + w; wid < n; wid += gridDim.x * 4) {
        float a0 = 0.f, a1 = 0.f, a2 = 0.f, a3 = 0.f;   // chain A
        float c0 = 0.f, c1 = 0.f, c2 = 0.f, c3 = 0.f;   // chain B
        if (half == 0) {        // self term
            uint2 u = h2[(size_t)wid * 32 + t];
            a0 = bl(u.x); a1 = bh(u.x); a2 = bl(u.y); a3 = bh(u.y);
        }
        int e0 = offs[wid], e1 = offs[wid + 1];
        int e = e0;
        while (e < e1) {        // wave-uniform
            int cnt = e1 - e;
            if (cnt > 64) cnt = 64;
            int sl = (lane < cnt) ? csr[e + lane] : 0;
            int j = 0;
            for (; j + 3 < cnt; j += 4) {       // 4 edges per iter, convergent
                int sa = __shfl(sl, j + half, 64);
                int sb = __shfl(sl, j + 2 + half, 64);
                uint2 ua = h2[(size_t)sa * 32 + t];
                uint2 ub = h2[(size_t)sb * 32 + t];
                a0 += bl(ua.x); a1 += bh(ua.x); a2 += bl(ua.y); a3 += bh(ua.y);
                c0 += bl(ub.x); c1 += bh(ub.x); c2 += bl(ub.y); c3 += bh(ub.y);
            }
            for (; j < cnt; j++) {              // leftovers, alternate halves
                int s = __shfl(sl, j, 64);      // convergent
                if (half == (j & 1)) {
                    uint2 u = h2[(size_t)s * 32 + t];
                    a0 += bl(u.x); a1 += bh(u.x); a2 += bl(u.y); a3 += bh(u.y);
                }
            }
            e += cnt;
        }
        a0 += c0; a1 += c1; a2 += c2; a3 += c3;
        a0 += __shfl_xor(a0, 32, 64);           // combine halves (convergent)
        a1 += __shfl_xor(a1, 32, 64);
        a2 += __shfl_xor(a2, 32, 64);
        a3 += __shfl_xor(a3, 32, 64);
        if (half == 0) {
            float di = dinv[wid];
            float v0 = a0 * di + bb.x;
            float v1 = a1 * di + bb.y;
            float v2 = a2 * di + bb.z;
            float v3 = a3 * di + bb.w;
            s0 += v0; q0 += v0 * v0;
            s1 += v1; q1 += v1 * v1;
            s2 += v2; q2 += v2 * v2;
            s3 += v3; q3 += v3 * v3;
            uint2 o;
            o.x = pack2(v0, v1);
            o.y = pack2(v2, v3);
            ((uint2*)out)[(size_t)wid * 32 + t] = o;
        }
    }
    // deterministic block reduce: [4 waves][32 cols-quads][4]
    __shared__ float LS[4][32][4], LQ[4][32][4];
    if (half == 0) {
        LS[w][t][0] = s0; LS[w][t][1] = s1; LS[w][t][2] = s2; LS[w][t][3] = s3;
        LQ[w][t][0] = q0; LQ[w][t][1] = q1; LQ[w][t][2] = q2; LQ[w][t][3] = q3;
    }
    __syncthreads();
    if (threadIdx.x < 128) {
        int cq = threadIdx.x >> 2, j = threadIdx.x & 3;
        float S = 0.f, Q = 0.f;
#pragma unroll
        for (int g = 0; g < 4; g++) { S += LS[g][cq][j]; Q += LQ[g][cq][j]; }
        psum[blockIdx.x * 128 + threadIdx.x] = S;
        psq[blockIdx.x * 128 + threadIdx.x] = Q;
    }
}

// 40-col aggregation + bias + log_softmax.  6 groups x 10 lanes, uint2 loads,
// 12 edges/iteration.  FULLY CONVERGENT shfls (clamped source, predicated loads).
__global__ __launch_bounds__(256) void agg40_lsm(const uint32* __restrict__ h,
                                                 const int* __restrict__ csr,
                                                 const int* __restrict__ offs,
                                                 const float* __restrict__ dinv,
                                                 const float* __restrict__ bias,
                                                 float* __restrict__ out, int n) {
    int wid = (blockIdx.x * 256 + threadIdx.x) >> 6;
    int lane = threadIdx.x & 63;
    if (wid >= n) return;
    int grp = lane / 10;              // 0..5 work; 6 (lanes 60-63) idle
    int t = lane - grp * 10;          // uint2 index within row (cols 4t..4t+3)
    bool work = grp < 6;
    const uint2* h2 = (const uint2*)h;
    float a0 = 0.f, a1 = 0.f, a2 = 0.f, a3 = 0.f;
    if (grp == 0) {                   // self term once
        uint2 u = h2[(size_t)wid * 10 + t];
        a0 = bl(u.x); a1 = bh(u.x); a2 = bl(u.y); a3 = bh(u.y);
    }
    int e0 = offs[wid], e1 = offs[wid + 1];
    int e = e0;
    while (e < e1) {                  // wave-uniform
        int cnt = e1 - e;
        if (cnt > 64) cnt = 64;
        int sl = (lane < cnt) ? csr[e + lane] : 0;
        int nIt = (cnt + 11) / 12;    // wave-uniform trip count
        for (int it = 0; it < nIt; it++) {
            int j0 = it * 12 + grp;
            int j1 = j0 + 6;
            int s0 = __shfl(sl, (j0 < cnt) ? j0 : 0, 64);   // convergent
            int s1 = __shfl(sl, (j1 < cnt) ? j1 : 0, 64);   // convergent
            if (work && j0 < cnt) {
                uint2 u = h2[(size_t)s0 * 10 + t];
                a0 += bl(u.x); a1 += bh(u.x); a2 += bl(u.y); a3 += bh(u.y);
            }
            if (work && j1 < cnt) {
                uint2 u = h2[(size_t)s1 * 10 + t];
                a0 += bl(u.x); a1 += bh(u.x); a2 += bl(u.y); a3 += bh(u.y);
            }
        }
        e += cnt;
    }
    // combine 6 groups: g += g+3, then grp0 += grp1 + grp2 (all convergent)
    a0 += __shfl(a0, (lane + 30) & 63, 64);
    a1 += __shfl(a1, (lane + 30) & 63, 64);
    a2 += __shfl(a2, (lane + 30) & 63, 64);
    a3 += __shfl(a3, (lane + 30) & 63, 64);
    {
        float t0 = __shfl(a0, (lane + 10) & 63, 64), u0 = __shfl(a0, (lane + 20) & 63, 64);
        float t1 = __shfl(a1, (lane + 10) & 63, 64), u1 = __shfl(a1, (lane + 20) & 63, 64);
        float t2 = __shfl(a2, (lane + 10) & 63, 64), u2 = __shfl(a2, (lane + 20) & 63, 64);
        float t3 = __shfl(a3, (lane + 10) & 63, 64), u3 = __shfl(a3, (lane + 20) & 63, 64);
        a0 += t0 + u0; a1 += t1 + u1; a2 += t2 + u2; a3 += t3 + u3;
    }
    bool act = lane < 10;
    float di = dinv[wid];
    float v0 = -1e30f, v1 = -1e30f, v2 = -1e30f, v3 = -1e30f;
    if (act) {
        float4 bb = ((const float4*)bias)[t];
        v0 = a0 * di + bb.x;
        v1 = a1 * di + bb.y;
        v2 = a2 * di + bb.z;
        v3 = a3 * di + bb.w;
    }
    float m = fmaxf(fmaxf(v0, v1), fmaxf(v2, v3));
    for (int off = 8; off; off >>= 1) m = fmaxf(m, __shfl_xor(m, off, 64));
    float ss = act ? (expf(v0 - m) + expf(v1 - m) + expf(v2 - m) + expf(v3 - m)) : 0.f;
    for (int off = 8; off; off >>= 1) ss += __shfl_xor(ss, off, 64);
    float lg = logf(ss);
    if (act) {
        float4 o = {v0 - m - lg, v1 - m - lg, v2 - m - lg, v3 - m - lg};
        *(float4*)&out[(size_t)wid * 40 + t * 4] = o;
    }
}

// ---------------- BN stats reduce (two parallel stages) ----------------

// stage 1: 128 blocks; block b sums partial rows [16b,16b+16) -> psum2[b][128]
__global__ __launch_bounds__(256) void reduce_ps(const float* __restrict__ psum,
                                                 const float* __restrict__ psq,
                                                 float* __restrict__ psum2,
                                                 float* __restrict__ psq2, int rpb) {
    int b = blockIdx.x;
    int c = threadIdx.x & 127;
    int half = threadIdx.x >> 7;      // 0/1
    float s = 0.f, q = 0.f;
    int r0 = b * rpb;
    for (int r = r0 + half; r < r0 + rpb; r += 2) {
        s += psum[(size_t)r * 128 + c];
        q += psq[(size_t)r * 128 + c];
    }
    __shared__ float LS[2][128], LQ[2][128];
    LS[half][c] = s;
    LQ[half][c] = q;
    __syncthreads();
    if (threadIdx.x < 128) {
        psum2[b * 128 + c] = LS[0][c] + LS[1][c];
        psq2[b * 128 + c] = LQ[0][c] + LQ[1][c];
    }
}

// stage 2: single block over nb=128 rows (64KB total -> fast)
__global__ __launch_bounds__(1024) void finalize_stats(const float* __restrict__ psum,
                                                       const float* __restrict__ psq,
                                                       const float* __restrict__ g,
                                                       const float* __restrict__ be,
                                                       float* __restrict__ scale,
                                                       float* __restrict__ shift,
                                                       int nb, float invN) {
    int c = threadIdx.x & 127;
    int seg = threadIdx.x >> 7;       // 0..7
    int per = nb >> 3;
    float s = 0.f, q = 0.f;
    for (int b = seg * per; b < (seg + 1) * per; b++) {
        s += psum[b * 128 + c];
        q += psq[b * 128 + c];
    }
    __shared__ float LS[8][128], LQ[8][128];
    LS[seg][c] = s;
    LQ[seg][c] = q;
    __syncthreads();
    if (threadIdx.x < 128) {
        float S = 0.f, Q = 0.f;
#pragma unroll
        for (int g2 = 0; g2 < 8; g2++) { S += LS[g2][c]; Q += LQ[g2][c]; }
        float mu = S * invN;
        float var = Q * invN - mu * mu;
        float sc = g[c] * rsqrtf(var + 1e-5f);
        scale[c] = sc;
        shift[c] = be[c] - mu * sc;
    }
}

extern "C" void kernel_launch(void* const* d_in, const int* in_sizes, int n_in,
                              void* d_out, int out_size, void* d_ws, size_t ws_size,
                              hipStream_t stream) {
    const float* x   = (const float*)d_in[0];
    const float* W1  = (const float*)d_in[1];
    const float* b1  = (const float*)d_in[2];
    const float* W2  = (const float*)d_in[3];
    const float* b2  = (const float*)d_in[4];
    const float* W3  = (const float*)d_in[5];
    const float* b3  = (const float*)d_in[6];
    const float* g1  = (const float*)d_in[7];
    const float* be1 = (const float*)d_in[8];
    const float* g2  = (const float*)d_in[9];
    const float* be2 = (const float*)d_in[10];
    const int*   ei  = (const int*)d_in[11];

    int n = in_sizes[0] / 128;
    int E = in_sizes[11] / 2;
    const int* src = ei;
    const int* dst = ei + E;
    int NB = (n + 127) >> 7;            // 128-node buckets

    char* p = (char*)d_ws;
    size_t off = 0;
    auto alloc = [&](size_t bytes) -> void* {
        off = (off + 255) & ~(size_t)255;
        void* r = p + off;
        off += bytes;
        return r;
    };
    uint32* hA    = (uint32*)alloc((size_t)n * 64 * 4);   // n x 128 bf16
    uint32* hB    = (uint32*)alloc((size_t)n * 64 * 4);
    float* dinv   = (float*)alloc((size_t)n * 4);
    int*   offs   = (int*)alloc((size_t)(n + 1) * 4);
    int*   csr    = (int*)alloc((size_t)E * 4);
    float* psum   = (float*)alloc((size_t)GSTAT * 128 * 4);
    float* psq    = (float*)alloc((size_t)GSTAT * 128 * 4);
    float* psum2  = (float*)alloc(128 * 128 * 4);
    float* psq2   = (float*)alloc(128 * 128 * 4);
    float* scale  = (float*)alloc(128 * 4);
    float* shift  = (float*)alloc(128 * 4);
    unsigned short* wt1 = (unsigned short*)alloc(128 * 128 * 2);
    unsigned short* wt2 = (unsigned short*)alloc(128 * 128 * 2);
    unsigned short* wt3 = (unsigned short*)alloc(48 * 128 * 2);
    int*   bcntp  = (int*)alloc((size_t)NB * 16 * 4);     // padded: 1 counter / 64B
    int*   boffs  = (int*)alloc((size_t)(NB + 1) * 4);
    int*   bcurp  = (int*)alloc((size_t)NB * 16 * 4);     // padded
    // bkt aliases hA: dead before the first gemm writes hA (stream-ordered)
    uint32* bkt   = hA;
    (void)ws_size;

    int gG = (n + 127) / 128;           // mfma-gemm blocks
    int gAgg = (n * 64 + 255) / 256;
    int gFill = (E + CSR_CH - 1) / CSR_CH;
    float invN = 1.0f / (float)n;

    hipMemsetAsync(bcntp, 0, (size_t)NB * 16 * 4, stream);

    wconv<<<3, 256, 0, stream>>>(W1, W2, W3, wt1, wt2, wt3);
    bucket_hist<<<256, 256, 0, stream>>>(dst, bcntp, E, NB);
    bucket_scan<<<1, 1024, 0, stream>>>(bcntp, boffs, bcurp, NB);
    bucket_fill2<<<gFill, 256, 0, stream>>>(src, dst, bcurp, bkt, E, NB);
    bucket_csr<<<NB, 256, 0, stream>>>(bkt, boffs, dinv, offs, csr, n);

    // layer 1
    gemm128m<false, false><<<gG, 256, 0, stream>>>(x, wt1, hA, dinv, n, nullptr, nullptr);
    agg128s<<<GSTAT, 256, 0, stream>>>(hA, csr, offs, dinv, b1, hB, psum, psq, n);
    reduce_ps<<<128, 256, 0, stream>>>(psum, psq, psum2, psq2, GSTAT / 128);
    finalize_stats<<<1, 1024, 0, stream>>>(psum2, psq2, g1, be1, scale, shift, 128, invN);

    // layer 2
    gemm128m<true, true><<<gG, 256, 0, stream>>>(hB, wt2, hA, dinv, n, scale, shift);
    agg128s<<<GSTAT, 256, 0, stream>>>(hA, csr, offs, dinv, b2, hB, psum, psq, n);
    reduce_ps<<<128, 256, 0, stream>>>(psum, psq, psum2, psq2, GSTAT / 128);
    finalize_stats<<<1, 1024, 0, stream>>>(psum2, psq2, g2, be2, scale, shift, 128, invN);

    // layer 3 + log_softmax
    gemm40m<<<gG, 256, 0, stream>>>(hB, wt3, (unsigned short*)hA, dinv, n, scale, shift);
    agg40_lsm<<<gAgg, 256, 0, stream>>>(hA, csr, offs, dinv, b3, (float*)d_out, n);
}